// Round 2
// baseline (284.984 us; speedup 1.0000x reference)
//
#include <hip/hip_runtime.h>

#define B_  4
#define NT_ 1024
#define NS_ 1024
#define D_  1024
#define H_  16
#define HD_ 64

typedef unsigned short u16;
typedef __attribute__((ext_vector_type(8))) short short8;
typedef __attribute__((ext_vector_type(4))) float f32x4;
typedef __attribute__((ext_vector_type(4))) unsigned short u16x4;

static __device__ __forceinline__ u16 f2bf(float f) {
  unsigned u = __builtin_bit_cast(unsigned, f);
  u += 0x7fff + ((u >> 16) & 1);          // RNE
  return (u16)(u >> 16);
}

static __device__ __forceinline__ f32x4 mfma16(short8 a, short8 b, f32x4 c) {
  return __builtin_amdgcn_mfma_f32_16x16x32_bf16(a, b, c, 0, 0, 0);
}

#define GLDS16(g, l) __builtin_amdgcn_global_load_lds( \
    (const __attribute__((address_space(1))) void*)(g), \
    (__attribute__((address_space(3))) void*)(l), 16, 0, 0)

// ---------------------------------------------------------------- convert
struct CvtArgs {
  const float* src[7];
  u16* dst[7];
  int n[7];
};

__global__ __launch_bounds__(256) void cvt_kernel(CvtArgs a) {
  const int z = blockIdx.z;
  const float* __restrict__ src = a.src[z];
  u16* __restrict__ dst = a.dst[z];
  const int n = a.n[z];
  int i = (blockIdx.x * 256 + threadIdx.x) * 4;
  const int stride = gridDim.x * 256 * 4;
  for (; i < n; i += stride) {
    float4 v = *reinterpret_cast<const float4*>(src + i);
    u16x4 o;
    o[0] = f2bf(v.x); o[1] = f2bf(v.y); o[2] = f2bf(v.z); o[3] = f2bf(v.w);
    *reinterpret_cast<u16x4*>(dst + i) = o;
  }
}

// ---------------------------------------------------------------- GEMM (B^T form)
// C[i][j] = sum_k A[i][k]*Bt[j][k] + bias[j].  128x128 tile, BK=32, 4 waves.
template<bool OBF16>
static __device__ __forceinline__ void gemm_body(
    const u16* __restrict__ A, const u16* __restrict__ Bt,
    const float* __restrict__ bias, void* __restrict__ Cout,
    const int N, const int K) {
  __shared__ u16 sA[128 * 32];
  __shared__ u16 sB[128 * 32];
  const int tid = threadIdx.x;
  const int wave = tid >> 6, lane = tid & 63;
  const int l15 = lane & 15, lq = lane >> 4;
  const size_t m0 = (size_t)blockIdx.y * 128;
  const size_t n0 = (size_t)blockIdx.x * 128;
  const int wr = (wave >> 1) * 64, wc = (wave & 1) * 64;
  f32x4 acc[4][4];
#pragma unroll
  for (int m = 0; m < 4; ++m)
#pragma unroll
    for (int n = 0; n < 4; ++n) acc[m][n] = (f32x4){0.f, 0.f, 0.f, 0.f};

  const int srow = lane >> 2;          // 0..15 within 16-row chunk
  const int scol = (lane & 3) * 8;     // 0,8,16,24

  for (int kt = 0; kt < K; kt += 32) {
#pragma unroll
    for (int i = 0; i < 2; ++i) {
      const int q = wave * 2 + i;      // 0..7 : 16-row chunk of the tile
      const u16* ga = A + (m0 + q * 16 + srow) * K + kt + scol;
      const u16* gb = Bt + (n0 + q * 16 + srow) * K + kt + scol;
      GLDS16(ga, sA + q * 512);
      GLDS16(gb, sB + q * 512);
    }
    __syncthreads();                   // drains vmcnt (global_load_lds) too
    short8 af[4], bfr[4];
#pragma unroll
    for (int m = 0; m < 4; ++m)
      af[m] = *reinterpret_cast<const short8*>(sA + (wr + m * 16 + l15) * 32 + lq * 8);
#pragma unroll
    for (int n = 0; n < 4; ++n)
      bfr[n] = *reinterpret_cast<const short8*>(sB + (wc + n * 16 + l15) * 32 + lq * 8);
#pragma unroll
    for (int m = 0; m < 4; ++m)
#pragma unroll
      for (int n = 0; n < 4; ++n)
        acc[m][n] = mfma16(af[m], bfr[n], acc[m][n]);
    __syncthreads();
  }
  // epilogue: C/D layout col=lane&15, row=(lane>>4)*4+r
#pragma unroll
  for (int m = 0; m < 4; ++m) {
    const size_t row0 = m0 + wr + m * 16 + lq * 4;
#pragma unroll
    for (int n = 0; n < 4; ++n) {
      const size_t col = n0 + wc + n * 16 + l15;
      const float bv = bias[col];
#pragma unroll
      for (int r = 0; r < 4; ++r) {
        const float v = acc[m][n][r] + bv;
        if (OBF16)
          ((u16*)Cout)[(row0 + r) * N + col] = f2bf(v);
        else
          ((float*)Cout)[(row0 + r) * N + col] = v;
      }
    }
  }
}

__global__ __launch_bounds__(256) void qkv_gemm_kernel(
    const u16* qb, const u16* kb, const u16* vb,
    const u16* wq, const u16* wk, const u16* wv,
    const float* bq, const float* bk, const float* bv,
    u16* qp, u16* kp, u16* vp) {
  const int z = blockIdx.z;
  const u16* A = (z == 0) ? qb : (z == 1) ? kb : vb;
  const u16* Bt = (z == 0) ? wq : (z == 1) ? wk : wv;
  const float* bias = (z == 0) ? bq : (z == 1) ? bk : bv;
  u16* C = (z == 0) ? qp : (z == 1) ? kp : vp;
  gemm_body<true>(A, Bt, bias, (void*)C, D_, D_);
}

__global__ __launch_bounds__(256) void oproj_kernel(
    const u16* __restrict__ A, const u16* __restrict__ Bt,
    const float* __restrict__ bias, float* __restrict__ C) {
  gemm_body<false>(A, Bt, bias, (void*)C, D_, D_);
}

// ---------------------------------------------------------------- V transpose
// vp [B, NS, D] -> vpT [B, H, HD, NS]
__global__ __launch_bounds__(256) void vtrans_kernel(const u16* __restrict__ vp,
                                                     u16* __restrict__ vpT) {
  __shared__ u16 t_lds[64][64];
  const int s0 = blockIdx.x * 64;
  const int h = blockIdx.y, b = blockIdx.z;
  const int tid = threadIdx.x;
  const int ri = tid >> 2;            // 0..63
  const int c0 = (tid & 3) * 16;      // 0,16,32,48
  const u16* src = vp + ((size_t)(b * NS_ + s0 + ri)) * D_ + h * HD_ + c0;
  *reinterpret_cast<short8*>(&t_lds[ri][c0]) = *reinterpret_cast<const short8*>(src);
  *reinterpret_cast<short8*>(&t_lds[ri][c0 + 8]) = *reinterpret_cast<const short8*>(src + 8);
  __syncthreads();
  short8 o1, o2;
#pragma unroll
  for (int j = 0; j < 8; ++j) o1[j] = (short)t_lds[c0 + j][ri];
#pragma unroll
  for (int j = 0; j < 8; ++j) o2[j] = (short)t_lds[c0 + 8 + j][ri];
  u16* dst = vpT + ((size_t)((b * H_ + h) * HD_ + ri)) * NS_ + s0 + c0;
  *reinterpret_cast<short8*>(dst) = o1;
  *reinterpret_cast<short8*>(dst + 8) = o2;
}

// ---------------------------------------------------------------- fused attention
// Block: (qtile 32 rows, h, b). 8 waves; wave w owns score cols [w*128,(w+1)*128).
// SWAPPED QK^T: acc = mfma(K_frag, Q_frag) -> D[s][t]: row(lq*4+r)=s-sub, col(l15)=t.
// Lane owns 4 consecutive s per register -> float4 mask loads / weight stores.
__global__ __launch_bounds__(512, 1) void attn_kernel(
    const u16* __restrict__ qp, const u16* __restrict__ kp,
    const u16* __restrict__ vpT, const float* __restrict__ mask,
    float* __restrict__ wout, u16* __restrict__ ctx) {
  __shared__ u16 Pl[32 * 1024];        // 64 KB, XOR-swizzled bf16 P
  __shared__ float red[32 * 8];
  __shared__ float rfin[32];

  const int qt = blockIdx.x, h = blockIdx.y, b = blockIdx.z;
  const int tid = threadIdx.x, wave = tid >> 6, lane = tid & 63;
  const int l15 = lane & 15, lq = lane >> 4;
  const int wcb = wave * 128;

  // Q fragments (B-operand): Q[t=mt*16+l15][d=ks*32+lq*8+..]
  short8 qf[2][2];
  const u16* qbase = qp + ((size_t)(b * NT_ + qt * 32)) * D_ + h * HD_;
#pragma unroll
  for (int mt = 0; mt < 2; ++mt)
#pragma unroll
    for (int ks = 0; ks < 2; ++ks)
      qf[mt][ks] = *reinterpret_cast<const short8*>(
          qbase + (size_t)(mt * 16 + l15) * D_ + ks * 32 + lq * 8);

  // K fragments (A-operand), all 16 prefetched: K[s=wcb+c*16+l15][d]
  short8 kf[8][2];
  const u16* kbase = kp + ((size_t)b * NS_) * D_ + h * HD_;
#pragma unroll
  for (int c = 0; c < 8; ++c)
#pragma unroll
    for (int ks = 0; ks < 2; ++ks)
      kf[c][ks] = *reinterpret_cast<const short8*>(
          kbase + (size_t)(wcb + c * 16 + l15) * D_ + ks * 32 + lq * 8);

  f32x4 acc[2][8];
#pragma unroll
  for (int mt = 0; mt < 2; ++mt)
#pragma unroll
    for (int c = 0; c < 8; ++c) acc[mt][c] = (f32x4){0.f, 0.f, 0.f, 0.f};

#pragma unroll
  for (int c = 0; c < 8; ++c)
#pragma unroll
    for (int ks = 0; ks < 2; ++ks) {
      acc[0][c] = mfma16(kf[c][ks], qf[0][ks], acc[0][c]);
      acc[1][c] = mfma16(kf[c][ks], qf[1][ks], acc[1][c]);
    }

  // mask (float4 per fragment) + scale
  float4 mk[2][8];
  const float* mbase = mask + (size_t)(qt * 32) * NS_ + wcb + lq * 4;
#pragma unroll
  for (int mt = 0; mt < 2; ++mt)
#pragma unroll
    for (int c = 0; c < 8; ++c)
      mk[mt][c] = *reinterpret_cast<const float4*>(
          mbase + (size_t)(mt * 16 + l15) * NS_ + c * 16);
#pragma unroll
  for (int mt = 0; mt < 2; ++mt)
#pragma unroll
    for (int c = 0; c < 8; ++c) {
      acc[mt][c][0] = acc[mt][c][0] * 0.125f + mk[mt][c].x;
      acc[mt][c][1] = acc[mt][c][1] * 0.125f + mk[mt][c].y;
      acc[mt][c][2] = acc[mt][c][2] * 0.125f + mk[mt][c].z;
      acc[mt][c][3] = acc[mt][c][3] * 0.125f + mk[mt][c].w;
    }

  // row max: 32 in-lane values + 2 shuffles (lanes sharing l15)
#pragma unroll
  for (int mt = 0; mt < 2; ++mt) {
    float v = -1e30f;
#pragma unroll
    for (int c = 0; c < 8; ++c)
#pragma unroll
      for (int r = 0; r < 4; ++r) v = fmaxf(v, acc[mt][c][r]);
    v = fmaxf(v, __shfl_xor(v, 16));
    v = fmaxf(v, __shfl_xor(v, 32));
    if (lane < 16) red[(mt * 16 + l15) * 8 + wave] = v;
  }
  __syncthreads();
  if (tid < 32) {
    float v = red[tid * 8];
#pragma unroll
    for (int w = 1; w < 8; ++w) v = fmaxf(v, red[tid * 8 + w]);
    rfin[tid] = v;
  }
  __syncthreads();
  float mx[2];
  mx[0] = rfin[l15];
  mx[1] = rfin[16 + l15];

  // exp + row sum
#pragma unroll
  for (int mt = 0; mt < 2; ++mt) {
    float s = 0.f;
#pragma unroll
    for (int c = 0; c < 8; ++c)
#pragma unroll
      for (int r = 0; r < 4; ++r) {
        const float e = __expf(acc[mt][c][r] - mx[mt]);
        acc[mt][c][r] = e;
        s += e;
      }
    s += __shfl_xor(s, 16);
    s += __shfl_xor(s, 32);
    if (lane < 16) red[(mt * 16 + l15) * 8 + wave] = s;
  }
  __syncthreads();
  if (tid < 32) {
    float s = 0.f;
#pragma unroll
    for (int w = 0; w < 8; ++w) s += red[tid * 8 + w];
    rfin[tid] = 1.0f / s;
  }
  __syncthreads();
  float rinv[2];
  rinv[0] = rfin[l15];
  rinv[1] = rfin[16 + l15];

  // write normalized weights (float4) + P (bf16x4, swizzled LDS)
#pragma unroll
  for (int mt = 0; mt < 2; ++mt) {
    const int t = mt * 16 + l15;
    float* wrow = wout + ((size_t)((b * H_ + h) * NT_ + qt * 32 + t)) * NS_ + wcb + lq * 4;
    u16* prow = Pl + t * 1024;
    const int swz = (t & 7) << 3;      // element-granule XOR (16B-byte granule)
#pragma unroll
    for (int c = 0; c < 8; ++c) {
      float4 w4;
      w4.x = acc[mt][c][0] * rinv[mt];
      w4.y = acc[mt][c][1] * rinv[mt];
      w4.z = acc[mt][c][2] * rinv[mt];
      w4.w = acc[mt][c][3] * rinv[mt];
      *reinterpret_cast<float4*>(wrow + c * 16) = w4;
      u16x4 p4;
      p4[0] = f2bf(w4.x); p4[1] = f2bf(w4.y); p4[2] = f2bf(w4.z); p4[3] = f2bf(w4.w);
      *reinterpret_cast<u16x4*>(prow + ((wcb + c * 16 + lq * 4) ^ swz)) = p4;
    }
  }
  __syncthreads();

  // Phase B: ctx[32][64] = P @ V.  wave -> (t-half, d-quarter)
  const int th = wave >> 2, dq = wave & 3;
  const int t2 = th * 16 + l15;

  // full V prefetch (32 x 16B = 128 VGPR; occupancy is LDS-bound so free)
  short8 vr[4][8];
  const u16* vbase = vpT + ((size_t)((b * H_ + h) * HD_ + dq * 16 + l15)) * NS_ + lq * 8;
#pragma unroll
  for (int g = 0; g < 4; ++g)
#pragma unroll
    for (int j = 0; j < 8; ++j)
      vr[g][j] = *reinterpret_cast<const short8*>(vbase + (g * 8 + j) * 32);

  const u16* prow2 = Pl + t2 * 1024;
  const int swz2 = (t2 & 7) << 3;
  f32x4 acc2 = (f32x4){0.f, 0.f, 0.f, 0.f};
  short8 pp[2][4];                      // ping-pong P groups of 4
#pragma unroll
  for (int j = 0; j < 4; ++j)
    pp[0][j] = *reinterpret_cast<const short8*>(prow2 + ((j * 32 + lq * 8) ^ swz2));
#pragma unroll
  for (int g = 0; g < 8; ++g) {
    if (g < 7) {
#pragma unroll
      for (int j = 0; j < 4; ++j)
        pp[(g + 1) & 1][j] = *reinterpret_cast<const short8*>(
            prow2 + ((((g + 1) * 4 + j) * 32 + lq * 8) ^ swz2));
    }
#pragma unroll
    for (int j = 0; j < 4; ++j) {
      const int ks = g * 4 + j;
      acc2 = mfma16(pp[g & 1][j], vr[ks >> 3][ks & 7], acc2);
    }
  }
  u16* cbase = ctx + ((size_t)(b * NT_ + qt * 32 + th * 16 + lq * 4)) * D_ + h * HD_ + dq * 16 + l15;
#pragma unroll
  for (int r = 0; r < 4; ++r) cbase[(size_t)r * D_] = f2bf(acc2[r]);
}

// ---------------------------------------------------------------- launch
extern "C" void kernel_launch(void* const* d_in, const int* in_sizes, int n_in,
                              void* d_out, int out_size, void* d_ws, size_t ws_size,
                              hipStream_t stream) {
  const float* q   = (const float*)d_in[0];
  const float* k   = (const float*)d_in[1];
  const float* v   = (const float*)d_in[2];
  const float* q_w = (const float*)d_in[3];
  const float* k_w = (const float*)d_in[4];
  const float* v_w = (const float*)d_in[5];
  const float* o_w = (const float*)d_in[6];
  const float* b_q = (const float*)d_in[7];
  const float* b_k = (const float*)d_in[8];
  const float* b_v = (const float*)d_in[9];
  const float* b_o = (const float*)d_in[10];
  const float* msk = (const float*)d_in[11];

  float* out = (float*)d_out;                       // [B,NT,D]
  float* wout = out + (size_t)B_ * NT_ * D_;        // [B,H,NT,NS]

  // workspace layout (bf16 elements)
  u16* qb = (u16*)d_ws;            // 4M   @0
  u16* kb = qb + 4194304;          //      @8MB
  u16* vb = kb + 4194304;          //      @16MB
  u16* wq = vb + 4194304;          // 1M   @24MB
  u16* wk = wq + 1048576;          //      @26MB
  u16* wv = wk + 1048576;          //      @28MB
  u16* wo = wv + 1048576;          //      @30MB
  u16* qp = wo + 1048576;          // 4M   @32MB
  u16* kp = qp + 4194304;          //      @40MB
  u16* vp = kp + 4194304;          //      @48MB  (total 56MB)
  u16* vpT = qb;                   // reuse: q bf16 dead after projections
  u16* ctx = kb;                   // reuse: k bf16 dead after projections

  CvtArgs ca;
  ca.src[0] = q;   ca.dst[0] = qb; ca.n[0] = B_ * NT_ * D_;
  ca.src[1] = k;   ca.dst[1] = kb; ca.n[1] = B_ * NS_ * D_;
  ca.src[2] = v;   ca.dst[2] = vb; ca.n[2] = B_ * NS_ * D_;
  ca.src[3] = q_w; ca.dst[3] = wq; ca.n[3] = D_ * D_;
  ca.src[4] = k_w; ca.dst[4] = wk; ca.n[4] = D_ * D_;
  ca.src[5] = v_w; ca.dst[5] = wv; ca.n[5] = D_ * D_;
  ca.src[6] = o_w; ca.dst[6] = wo; ca.n[6] = D_ * D_;
  cvt_kernel<<<dim3(1024, 1, 7), 256, 0, stream>>>(ca);

  qkv_gemm_kernel<<<dim3(8, 32, 3), 256, 0, stream>>>(
      qb, kb, vb, wq, wk, wv, b_q, b_k, b_v, qp, kp, vp);

  vtrans_kernel<<<dim3(16, 16, 4), 256, 0, stream>>>(vp, vpT);

  attn_kernel<<<dim3(32, 16, 4), 512, 0, stream>>>(qp, kp, vpT, msk, wout, ctx);

  oproj_kernel<<<dim3(8, 32), 256, 0, stream>>>(ctx, wo, b_o, out);
}

// Round 3
// 276.222 us; speedup vs baseline: 1.0317x; 1.0317x over previous
//
#include <hip/hip_runtime.h>

#define B_  4
#define NT_ 1024
#define NS_ 1024
#define D_  1024
#define H_  16
#define HD_ 64

typedef unsigned short u16;
typedef __attribute__((ext_vector_type(8))) short short8;
typedef __attribute__((ext_vector_type(4))) float f32x4;
typedef __attribute__((ext_vector_type(4))) unsigned short u16x4;

static __device__ __forceinline__ u16 f2bf(float f) {
  unsigned u = __builtin_bit_cast(unsigned, f);
  u += 0x7fff + ((u >> 16) & 1);          // RNE
  return (u16)(u >> 16);
}

static __device__ __forceinline__ f32x4 mfma16(short8 a, short8 b, f32x4 c) {
  return __builtin_amdgcn_mfma_f32_16x16x32_bf16(a, b, c, 0, 0, 0);
}

#define GLDS16(g, l) __builtin_amdgcn_global_load_lds( \
    (const __attribute__((address_space(1))) void*)(g), \
    (__attribute__((address_space(3))) void*)(l), 16, 0, 0)

// ---------------------------------------------------------------- convert
struct CvtArgs {
  const float* src[7];
  u16* dst[7];
  int n[7];
};

__global__ __launch_bounds__(256) void cvt_kernel(CvtArgs a) {
  const int z = blockIdx.z;
  const float* __restrict__ src = a.src[z];
  u16* __restrict__ dst = a.dst[z];
  const int n = a.n[z];
  int i = (blockIdx.x * 256 + threadIdx.x) * 4;
  const int stride = gridDim.x * 256 * 4;
  for (; i < n; i += stride) {
    float4 v = *reinterpret_cast<const float4*>(src + i);
    u16x4 o;
    o[0] = f2bf(v.x); o[1] = f2bf(v.y); o[2] = f2bf(v.z); o[3] = f2bf(v.w);
    *reinterpret_cast<u16x4*>(dst + i) = o;
  }
}

// ---------------------------------------------------------------- GEMM (B^T form)
// C[i][j] = sum_k A[i][k]*Bt[j][k] + bias[j].  128x128 tile, BK=32, 4 waves.
template<bool OBF16>
static __device__ __forceinline__ void gemm_body(
    const u16* __restrict__ A, const u16* __restrict__ Bt,
    const float* __restrict__ bias, void* __restrict__ Cout,
    const int N, const int K) {
  __shared__ u16 sA[128 * 32];
  __shared__ u16 sB[128 * 32];
  const int tid = threadIdx.x;
  const int wave = tid >> 6, lane = tid & 63;
  const int l15 = lane & 15, lq = lane >> 4;
  const size_t m0 = (size_t)blockIdx.y * 128;
  const size_t n0 = (size_t)blockIdx.x * 128;
  const int wr = (wave >> 1) * 64, wc = (wave & 1) * 64;
  f32x4 acc[4][4];
#pragma unroll
  for (int m = 0; m < 4; ++m)
#pragma unroll
    for (int n = 0; n < 4; ++n) acc[m][n] = (f32x4){0.f, 0.f, 0.f, 0.f};

  const int srow = lane >> 2;          // 0..15 within 16-row chunk
  const int scol = (lane & 3) * 8;     // 0,8,16,24

  for (int kt = 0; kt < K; kt += 32) {
#pragma unroll
    for (int i = 0; i < 2; ++i) {
      const int q = wave * 2 + i;      // 0..7 : 16-row chunk of the tile
      const u16* ga = A + (m0 + q * 16 + srow) * K + kt + scol;
      const u16* gb = Bt + (n0 + q * 16 + srow) * K + kt + scol;
      GLDS16(ga, sA + q * 512);
      GLDS16(gb, sB + q * 512);
    }
    __syncthreads();                   // drains vmcnt (global_load_lds) too
    short8 af[4], bfr[4];
#pragma unroll
    for (int m = 0; m < 4; ++m)
      af[m] = *reinterpret_cast<const short8*>(sA + (wr + m * 16 + l15) * 32 + lq * 8);
#pragma unroll
    for (int n = 0; n < 4; ++n)
      bfr[n] = *reinterpret_cast<const short8*>(sB + (wc + n * 16 + l15) * 32 + lq * 8);
#pragma unroll
    for (int m = 0; m < 4; ++m)
#pragma unroll
      for (int n = 0; n < 4; ++n)
        acc[m][n] = mfma16(af[m], bfr[n], acc[m][n]);
    __syncthreads();
  }
  // epilogue: C/D layout col=lane&15, row=(lane>>4)*4+r
#pragma unroll
  for (int m = 0; m < 4; ++m) {
    const size_t row0 = m0 + wr + m * 16 + lq * 4;
#pragma unroll
    for (int n = 0; n < 4; ++n) {
      const size_t col = n0 + wc + n * 16 + l15;
      const float bv = bias[col];
#pragma unroll
      for (int r = 0; r < 4; ++r) {
        const float v = acc[m][n][r] + bv;
        if (OBF16)
          ((u16*)Cout)[(row0 + r) * N + col] = f2bf(v);
        else
          ((float*)Cout)[(row0 + r) * N + col] = v;
      }
    }
  }
}

__global__ __launch_bounds__(256) void qkv_gemm_kernel(
    const u16* qb, const u16* kb, const u16* vb,
    const u16* wq, const u16* wk, const u16* wv,
    const float* bq, const float* bk, const float* bv,
    u16* qp, u16* kp, u16* vp) {
  const int z = blockIdx.z;
  const u16* A = (z == 0) ? qb : (z == 1) ? kb : vb;
  const u16* Bt = (z == 0) ? wq : (z == 1) ? wk : wv;
  const float* bias = (z == 0) ? bq : (z == 1) ? bk : bv;
  u16* C = (z == 0) ? qp : (z == 1) ? kp : vp;
  gemm_body<true>(A, Bt, bias, (void*)C, D_, D_);
}

__global__ __launch_bounds__(256) void oproj_kernel(
    const u16* __restrict__ A, const u16* __restrict__ Bt,
    const float* __restrict__ bias, float* __restrict__ C) {
  gemm_body<false>(A, Bt, bias, (void*)C, D_, D_);
}

// ---------------------------------------------------------------- V transpose
// vp [B, NS, D] -> vpT [B, H, HD, NS]
__global__ __launch_bounds__(256) void vtrans_kernel(const u16* __restrict__ vp,
                                                     u16* __restrict__ vpT) {
  __shared__ u16 t_lds[64][64];
  const int s0 = blockIdx.x * 64;
  const int h = blockIdx.y, b = blockIdx.z;
  const int tid = threadIdx.x;
  const int ri = tid >> 2;            // 0..63
  const int c0 = (tid & 3) * 16;      // 0,16,32,48
  const u16* src = vp + ((size_t)(b * NS_ + s0 + ri)) * D_ + h * HD_ + c0;
  *reinterpret_cast<short8*>(&t_lds[ri][c0]) = *reinterpret_cast<const short8*>(src);
  *reinterpret_cast<short8*>(&t_lds[ri][c0 + 8]) = *reinterpret_cast<const short8*>(src + 8);
  __syncthreads();
  short8 o1, o2;
#pragma unroll
  for (int j = 0; j < 8; ++j) o1[j] = (short)t_lds[c0 + j][ri];
#pragma unroll
  for (int j = 0; j < 8; ++j) o2[j] = (short)t_lds[c0 + 8 + j][ri];
  u16* dst = vpT + ((size_t)((b * H_ + h) * HD_ + ri)) * NS_ + s0 + c0;
  *reinterpret_cast<short8*>(dst) = o1;
  *reinterpret_cast<short8*>(dst + 8) = o2;
}

// ---------------------------------------------------------------- fused attention
// Block: (qtile 16 rows, h, b). 8 waves; wave w owns score cols [w*128,(w+1)*128).
// SWAPPED QK^T: acc = mfma(K_frag, Q_frag) -> D[s][t]: row(lq*4+r)=s-sub, col(l15)=t.
// P buffer is only [16][1024] bf16 = 32KB -> ~37KB LDS total -> 2 blocks/CU.
// PV: wave = (kh, dq): k-half x d-quarter; halves combined via 4KB LDS partials.
__global__ __launch_bounds__(512, 4) void attn_kernel(
    const u16* __restrict__ qp, const u16* __restrict__ kp,
    const u16* __restrict__ vpT, const float* __restrict__ mask,
    float* __restrict__ wout, u16* __restrict__ ctx) {
  __shared__ u16 Pl[16 * 1024];        // 32 KB, XOR-swizzled bf16 P
  __shared__ float ctxp[16 * 64];      // 4 KB partial ctx (k-half 0)
  __shared__ float red[16 * 8];
  __shared__ float rfin[16];

  const int qt = blockIdx.x, h = blockIdx.y, b = blockIdx.z;
  const int tid = threadIdx.x, wave = tid >> 6, lane = tid & 63;
  const int l15 = lane & 15, lq = lane >> 4;
  const int wcb = wave * 128;

  // Q fragments (B-operand): Q[t=l15][d=ks*32+lq*8+..]
  short8 qf[2];
  const u16* qbase = qp + ((size_t)(b * NT_ + qt * 16)) * D_ + h * HD_;
#pragma unroll
  for (int ks = 0; ks < 2; ++ks)
    qf[ks] = *reinterpret_cast<const short8*>(
        qbase + (size_t)l15 * D_ + ks * 32 + lq * 8);

  // K fragments (A-operand): K[s=wcb+c*16+l15][d]
  const u16* kbase = kp + ((size_t)b * NS_) * D_ + h * HD_;
  f32x4 acc[8];
#pragma unroll
  for (int c = 0; c < 8; ++c) acc[c] = (f32x4){0.f, 0.f, 0.f, 0.f};
#pragma unroll
  for (int c = 0; c < 8; ++c)
#pragma unroll
    for (int ks = 0; ks < 2; ++ks) {
      short8 kf = *reinterpret_cast<const short8*>(
          kbase + (size_t)(wcb + c * 16 + l15) * D_ + ks * 32 + lq * 8);
      acc[c] = mfma16(kf, qf[ks], acc[c]);
    }

  // mask (float4 per fragment) + scale
  const float* mbase = mask + (size_t)(qt * 16) * NS_ + wcb + lq * 4;
#pragma unroll
  for (int c = 0; c < 8; ++c) {
    float4 mk = *reinterpret_cast<const float4*>(
        mbase + (size_t)l15 * NS_ + c * 16);
    acc[c][0] = acc[c][0] * 0.125f + mk.x;
    acc[c][1] = acc[c][1] * 0.125f + mk.y;
    acc[c][2] = acc[c][2] * 0.125f + mk.z;
    acc[c][3] = acc[c][3] * 0.125f + mk.w;
  }

  // row max: 32 in-lane values + 2 shuffles (lanes sharing l15)
  {
    float v = -1e30f;
#pragma unroll
    for (int c = 0; c < 8; ++c)
#pragma unroll
      for (int r = 0; r < 4; ++r) v = fmaxf(v, acc[c][r]);
    v = fmaxf(v, __shfl_xor(v, 16));
    v = fmaxf(v, __shfl_xor(v, 32));
    if (lane < 16) red[l15 * 8 + wave] = v;
  }
  __syncthreads();
  if (tid < 16) {
    float v = red[tid * 8];
#pragma unroll
    for (int w = 1; w < 8; ++w) v = fmaxf(v, red[tid * 8 + w]);
    rfin[tid] = v;
  }
  __syncthreads();
  const float mx = rfin[l15];

  // exp + row sum
  {
    float s = 0.f;
#pragma unroll
    for (int c = 0; c < 8; ++c)
#pragma unroll
      for (int r = 0; r < 4; ++r) {
        const float e = __expf(acc[c][r] - mx);
        acc[c][r] = e;
        s += e;
      }
    s += __shfl_xor(s, 16);
    s += __shfl_xor(s, 32);
    if (lane < 16) red[l15 * 8 + wave] = s;
  }
  __syncthreads();
  if (tid < 16) {
    float s = 0.f;
#pragma unroll
    for (int w = 0; w < 8; ++w) s += red[tid * 8 + w];
    rfin[tid] = 1.0f / s;
  }
  __syncthreads();
  const float rinv = rfin[l15];

  // write normalized weights (nontemporal f32x4) + P (bf16x4, swizzled LDS)
  {
    const int t = l15;
    float* wrow = wout + ((size_t)((b * H_ + h) * NT_ + qt * 16 + t)) * NS_ + wcb + lq * 4;
    u16* prow = Pl + t * 1024;
    const int swz = (t & 7) << 3;      // 16B-granule XOR in element units
#pragma unroll
    for (int c = 0; c < 8; ++c) {
      f32x4 w4;
      w4[0] = acc[c][0] * rinv;
      w4[1] = acc[c][1] * rinv;
      w4[2] = acc[c][2] * rinv;
      w4[3] = acc[c][3] * rinv;
      __builtin_nontemporal_store(w4, reinterpret_cast<f32x4*>(wrow + c * 16));
      u16x4 p4;
      p4[0] = f2bf(w4[0]); p4[1] = f2bf(w4[1]); p4[2] = f2bf(w4[2]); p4[3] = f2bf(w4[3]);
      *reinterpret_cast<u16x4*>(prow + ((wcb + c * 16 + lq * 4) ^ swz)) = p4;
    }
  }
  __syncthreads();

  // Phase B: ctx[16][64] = P @ V.  wave -> (k-half, d-quarter)
  const int kh = wave >> 2, dq = wave & 3;
  const u16* prow2 = Pl + l15 * 1024;           // A-frag row t = l15
  const int swz2 = (l15 & 7) << 3;
  const u16* vbase = vpT + ((size_t)((b * H_ + h) * HD_ + dq * 16 + l15)) * NS_
                   + kh * 512 + lq * 8;
  f32x4 acc2 = (f32x4){0.f, 0.f, 0.f, 0.f};
#pragma unroll
  for (int ks = 0; ks < 16; ++ks) {
    short8 pa = *reinterpret_cast<const short8*>(
        prow2 + ((kh * 512 + ks * 32 + lq * 8) ^ swz2));
    short8 vf = *reinterpret_cast<const short8*>(vbase + ks * 32);
    acc2 = mfma16(pa, vf, acc2);
  }
  // combine k-halves: kh=0 stores partial to LDS, kh=1 adds and writes out
  if (kh == 0) {
#pragma unroll
    for (int r = 0; r < 4; ++r)
      ctxp[(lq * 4 + r) * 64 + dq * 16 + l15] = acc2[r];
  }
  __syncthreads();
  if (kh == 1) {
    u16* cbase = ctx + ((size_t)(b * NT_ + qt * 16 + lq * 4)) * D_ + h * HD_ + dq * 16 + l15;
#pragma unroll
    for (int r = 0; r < 4; ++r) {
      const float v = acc2[r] + ctxp[(lq * 4 + r) * 64 + dq * 16 + l15];
      cbase[(size_t)r * D_] = f2bf(v);
    }
  }
}

// ---------------------------------------------------------------- launch
extern "C" void kernel_launch(void* const* d_in, const int* in_sizes, int n_in,
                              void* d_out, int out_size, void* d_ws, size_t ws_size,
                              hipStream_t stream) {
  const float* q   = (const float*)d_in[0];
  const float* k   = (const float*)d_in[1];
  const float* v   = (const float*)d_in[2];
  const float* q_w = (const float*)d_in[3];
  const float* k_w = (const float*)d_in[4];
  const float* v_w = (const float*)d_in[5];
  const float* o_w = (const float*)d_in[6];
  const float* b_q = (const float*)d_in[7];
  const float* b_k = (const float*)d_in[8];
  const float* b_v = (const float*)d_in[9];
  const float* b_o = (const float*)d_in[10];
  const float* msk = (const float*)d_in[11];

  float* out = (float*)d_out;                       // [B,NT,D]
  float* wout = out + (size_t)B_ * NT_ * D_;        // [B,H,NT,NS]

  // workspace layout (bf16 elements)
  u16* qb = (u16*)d_ws;            // 4M   @0
  u16* kb = qb + 4194304;          //      @8MB
  u16* vb = kb + 4194304;          //      @16MB
  u16* wq = vb + 4194304;          // 1M   @24MB
  u16* wk = wq + 1048576;          //      @26MB
  u16* wv = wk + 1048576;          //      @28MB
  u16* wo = wv + 1048576;          //      @30MB
  u16* qp = wo + 1048576;          // 4M   @32MB
  u16* kp = qp + 4194304;          //      @40MB
  u16* vp = kp + 4194304;          //      @48MB  (total 56MB)
  u16* vpT = qb;                   // reuse: q bf16 dead after projections
  u16* ctx = kb;                   // reuse: k bf16 dead after projections

  CvtArgs ca;
  ca.src[0] = q;   ca.dst[0] = qb; ca.n[0] = B_ * NT_ * D_;
  ca.src[1] = k;   ca.dst[1] = kb; ca.n[1] = B_ * NS_ * D_;
  ca.src[2] = v;   ca.dst[2] = vb; ca.n[2] = B_ * NS_ * D_;
  ca.src[3] = q_w; ca.dst[3] = wq; ca.n[3] = D_ * D_;
  ca.src[4] = k_w; ca.dst[4] = wk; ca.n[4] = D_ * D_;
  ca.src[5] = v_w; ca.dst[5] = wv; ca.n[5] = D_ * D_;
  ca.src[6] = o_w; ca.dst[6] = wo; ca.n[6] = D_ * D_;
  cvt_kernel<<<dim3(1024, 1, 7), 256, 0, stream>>>(ca);

  qkv_gemm_kernel<<<dim3(8, 32, 3), 256, 0, stream>>>(
      qb, kb, vb, wq, wk, wv, b_q, b_k, b_v, qp, kp, vp);

  vtrans_kernel<<<dim3(16, 16, 4), 256, 0, stream>>>(vp, vpT);

  attn_kernel<<<dim3(64, 16, 4), 512, 0, stream>>>(qp, kp, vpT, msk, wout, ctx);

  oproj_kernel<<<dim3(8, 32), 256, 0, stream>>>(ctx, wo, b_o, out);
}

// Round 4
// 255.143 us; speedup vs baseline: 1.1170x; 1.0826x over previous
//
#include <hip/hip_runtime.h>

#define B_  4
#define NT_ 1024
#define NS_ 1024
#define D_  1024
#define H_  16
#define HD_ 64

typedef unsigned short u16;
typedef __attribute__((ext_vector_type(8))) short short8;
typedef __attribute__((ext_vector_type(4))) float f32x4;
typedef __attribute__((ext_vector_type(4))) unsigned short u16x4;

static __device__ __forceinline__ u16 f2bf(float f) {
  unsigned u = __builtin_bit_cast(unsigned, f);
  u += 0x7fff + ((u >> 16) & 1);          // RNE
  return (u16)(u >> 16);
}

static __device__ __forceinline__ float bf2f(u16 h) {
  return __builtin_bit_cast(float, (unsigned)h << 16);
}

static __device__ __forceinline__ f32x4 mfma16(short8 a, short8 b, f32x4 c) {
  return __builtin_amdgcn_mfma_f32_16x16x32_bf16(a, b, c, 0, 0, 0);
}

#define GLDS16(g, l) __builtin_amdgcn_global_load_lds( \
    (const __attribute__((address_space(1))) void*)(g), \
    (__attribute__((address_space(3))) void*)(l), 16, 0, 0)

// ---------------------------------------------------------------- convert
struct CvtArgs {
  const float* src[7];
  u16* dst[7];
  int n[7];
};

__global__ __launch_bounds__(256) void cvt_kernel(CvtArgs a) {
  const int z = blockIdx.z;
  const float* __restrict__ src = a.src[z];
  u16* __restrict__ dst = a.dst[z];
  const int n = a.n[z];
  int i = (blockIdx.x * 256 + threadIdx.x) * 4;
  const int stride = gridDim.x * 256 * 4;
  for (; i < n; i += stride) {
    float4 v = *reinterpret_cast<const float4*>(src + i);
    u16x4 o;
    o[0] = f2bf(v.x); o[1] = f2bf(v.y); o[2] = f2bf(v.z); o[3] = f2bf(v.w);
    *reinterpret_cast<u16x4*>(dst + i) = o;
  }
}

// ---------------------------------------------------------------- GEMM (B^T form)
// C[i][j] = sum_k A[i][k]*Bt[j][k] + bias[j].  128x128 tile, BK=32, 4 waves.
template<bool OBF16>
static __device__ __forceinline__ void gemm_body(
    const u16* __restrict__ A, const u16* __restrict__ Bt,
    const float* __restrict__ bias, void* __restrict__ Cout,
    const int N, const int K) {
  __shared__ u16 sA[128 * 32];
  __shared__ u16 sB[128 * 32];
  const int tid = threadIdx.x;
  const int wave = tid >> 6, lane = tid & 63;
  const int l15 = lane & 15, lq = lane >> 4;
  const size_t m0 = (size_t)blockIdx.y * 128;
  const size_t n0 = (size_t)blockIdx.x * 128;
  const int wr = (wave >> 1) * 64, wc = (wave & 1) * 64;
  f32x4 acc[4][4];
#pragma unroll
  for (int m = 0; m < 4; ++m)
#pragma unroll
    for (int n = 0; n < 4; ++n) acc[m][n] = (f32x4){0.f, 0.f, 0.f, 0.f};

  const int srow = lane >> 2;          // 0..15 within 16-row chunk
  const int scol = (lane & 3) * 8;     // 0,8,16,24

  for (int kt = 0; kt < K; kt += 32) {
#pragma unroll
    for (int i = 0; i < 2; ++i) {
      const int q = wave * 2 + i;      // 0..7 : 16-row chunk of the tile
      const u16* ga = A + (m0 + q * 16 + srow) * K + kt + scol;
      const u16* gb = Bt + (n0 + q * 16 + srow) * K + kt + scol;
      GLDS16(ga, sA + q * 512);
      GLDS16(gb, sB + q * 512);
    }
    __syncthreads();                   // drains vmcnt (global_load_lds) too
    short8 af[4], bfr[4];
#pragma unroll
    for (int m = 0; m < 4; ++m)
      af[m] = *reinterpret_cast<const short8*>(sA + (wr + m * 16 + l15) * 32 + lq * 8);
#pragma unroll
    for (int n = 0; n < 4; ++n)
      bfr[n] = *reinterpret_cast<const short8*>(sB + (wc + n * 16 + l15) * 32 + lq * 8);
#pragma unroll
    for (int m = 0; m < 4; ++m)
#pragma unroll
      for (int n = 0; n < 4; ++n)
        acc[m][n] = mfma16(af[m], bfr[n], acc[m][n]);
    __syncthreads();
  }
  // epilogue: C/D layout col=lane&15, row=(lane>>4)*4+r
#pragma unroll
  for (int m = 0; m < 4; ++m) {
    const size_t row0 = m0 + wr + m * 16 + lq * 4;
#pragma unroll
    for (int n = 0; n < 4; ++n) {
      const size_t col = n0 + wc + n * 16 + l15;
      const float bv = bias[col];
#pragma unroll
      for (int r = 0; r < 4; ++r) {
        const float v = acc[m][n][r] + bv;
        if (OBF16)
          ((u16*)Cout)[(row0 + r) * N + col] = f2bf(v);
        else
          ((float*)Cout)[(row0 + r) * N + col] = v;
      }
    }
  }
}

__global__ __launch_bounds__(256) void qkv_gemm_kernel(
    const u16* qb, const u16* kb, const u16* vb,
    const u16* wq, const u16* wk, const u16* wv,
    const float* bq, const float* bk, const float* bv,
    u16* qp, u16* kp, u16* vp) {
  const int z = blockIdx.z;
  const u16* A = (z == 0) ? qb : (z == 1) ? kb : vb;
  const u16* Bt = (z == 0) ? wq : (z == 1) ? wk : wv;
  const float* bias = (z == 0) ? bq : (z == 1) ? bk : bv;
  u16* C = (z == 0) ? qp : (z == 1) ? kp : vp;
  gemm_body<true>(A, Bt, bias, (void*)C, D_, D_);
}

__global__ __launch_bounds__(256) void oproj_kernel(
    const u16* __restrict__ A, const u16* __restrict__ Bt,
    const float* __restrict__ bias, float* __restrict__ C) {
  gemm_body<false>(A, Bt, bias, (void*)C, D_, D_);
}

// ---------------------------------------------------------------- V transpose
// vp [B, NS, D] -> vpT [B, H, HD, NS]
__global__ __launch_bounds__(256) void vtrans_kernel(const u16* __restrict__ vp,
                                                     u16* __restrict__ vpT) {
  __shared__ u16 t_lds[64][64];
  const int s0 = blockIdx.x * 64;
  const int h = blockIdx.y, b = blockIdx.z;
  const int tid = threadIdx.x;
  const int ri = tid >> 2;            // 0..63
  const int c0 = (tid & 3) * 16;      // 0,16,32,48
  const u16* src = vp + ((size_t)(b * NS_ + s0 + ri)) * D_ + h * HD_ + c0;
  *reinterpret_cast<short8*>(&t_lds[ri][c0]) = *reinterpret_cast<const short8*>(src);
  *reinterpret_cast<short8*>(&t_lds[ri][c0 + 8]) = *reinterpret_cast<const short8*>(src + 8);
  __syncthreads();
  short8 o1, o2;
#pragma unroll
  for (int j = 0; j < 8; ++j) o1[j] = (short)t_lds[c0 + j][ri];
#pragma unroll
  for (int j = 0; j < 8; ++j) o2[j] = (short)t_lds[c0 + 8 + j][ri];
  u16* dst = vpT + ((size_t)((b * H_ + h) * HD_ + ri)) * NS_ + s0 + c0;
  *reinterpret_cast<short8*>(dst) = o1;
  *reinterpret_cast<short8*>(dst + 8) = o2;
}

// ---------------------------------------------------------------- fused attention
// Block: (qtile 16 rows, h, b). 8 waves; wave w owns score cols [w*128,(w+1)*128).
// SWAPPED QK^T: acc = mfma(K_frag, Q_frag) -> D[s][t]: row(lq*4+r)=s-sub, col(l15)=t.
// Normalized weights go ONLY to LDS (bf16 P); wout is then written back from P
// with fully-coalesced 512B-per-halfwave nontemporal streams.
__global__ __launch_bounds__(512, 4) void attn_kernel(
    const u16* __restrict__ qp, const u16* __restrict__ kp,
    const u16* __restrict__ vpT, const float* __restrict__ mask,
    float* __restrict__ wout, u16* __restrict__ ctx) {
  __shared__ u16 Pl[16 * 1024];        // 32 KB, XOR-swizzled bf16 P
  __shared__ float ctxp[16 * 64];      // 4 KB partial ctx (k-half 0)
  __shared__ float red[16 * 8];
  __shared__ float rfin[16];

  const int qt = blockIdx.x, h = blockIdx.y, b = blockIdx.z;
  const int tid = threadIdx.x, wave = tid >> 6, lane = tid & 63;
  const int l15 = lane & 15, lq = lane >> 4;
  const int wcb = wave * 128;

  // Q fragments (B-operand): Q[t=l15][d=ks*32+lq*8+..]
  short8 qf[2];
  const u16* qbase = qp + ((size_t)(b * NT_ + qt * 16)) * D_ + h * HD_;
#pragma unroll
  for (int ks = 0; ks < 2; ++ks)
    qf[ks] = *reinterpret_cast<const short8*>(
        qbase + (size_t)l15 * D_ + ks * 32 + lq * 8);

  // K fragments (A-operand): K[s=wcb+c*16+l15][d]
  const u16* kbase = kp + ((size_t)b * NS_) * D_ + h * HD_;
  f32x4 acc[8];
#pragma unroll
  for (int c = 0; c < 8; ++c) acc[c] = (f32x4){0.f, 0.f, 0.f, 0.f};
#pragma unroll
  for (int c = 0; c < 8; ++c)
#pragma unroll
    for (int ks = 0; ks < 2; ++ks) {
      short8 kf = *reinterpret_cast<const short8*>(
          kbase + (size_t)(wcb + c * 16 + l15) * D_ + ks * 32 + lq * 8);
      acc[c] = mfma16(kf, qf[ks], acc[c]);
    }

  // mask (float4 per fragment) + scale
  const float* mbase = mask + (size_t)(qt * 16) * NS_ + wcb + lq * 4;
#pragma unroll
  for (int c = 0; c < 8; ++c) {
    float4 mk = *reinterpret_cast<const float4*>(
        mbase + (size_t)l15 * NS_ + c * 16);
    acc[c][0] = acc[c][0] * 0.125f + mk.x;
    acc[c][1] = acc[c][1] * 0.125f + mk.y;
    acc[c][2] = acc[c][2] * 0.125f + mk.z;
    acc[c][3] = acc[c][3] * 0.125f + mk.w;
  }

  // row max: 32 in-lane values + 2 shuffles (lanes sharing l15)
  {
    float v = -1e30f;
#pragma unroll
    for (int c = 0; c < 8; ++c)
#pragma unroll
      for (int r = 0; r < 4; ++r) v = fmaxf(v, acc[c][r]);
    v = fmaxf(v, __shfl_xor(v, 16));
    v = fmaxf(v, __shfl_xor(v, 32));
    if (lane < 16) red[l15 * 8 + wave] = v;
  }
  __syncthreads();
  if (tid < 16) {
    float v = red[tid * 8];
#pragma unroll
    for (int w = 1; w < 8; ++w) v = fmaxf(v, red[tid * 8 + w]);
    rfin[tid] = v;
  }
  __syncthreads();
  const float mx = rfin[l15];

  // exp + row sum
  {
    float s = 0.f;
#pragma unroll
    for (int c = 0; c < 8; ++c)
#pragma unroll
      for (int r = 0; r < 4; ++r) {
        const float e = __expf(acc[c][r] - mx);
        acc[c][r] = e;
        s += e;
      }
    s += __shfl_xor(s, 16);
    s += __shfl_xor(s, 32);
    if (lane < 16) red[l15 * 8 + wave] = s;
  }
  __syncthreads();
  if (tid < 16) {
    float s = 0.f;
#pragma unroll
    for (int w = 0; w < 8; ++w) s += red[tid * 8 + w];
    rfin[tid] = 1.0f / s;
  }
  __syncthreads();
  const float rinv = rfin[l15];

  // P (bf16x4, swizzled LDS) -- sole carrier of normalized weights
  {
    const int t = l15;
    u16* prow = Pl + t * 1024;
    const int swz = (t & 7) << 3;      // 16B-granule XOR in element units
#pragma unroll
    for (int c = 0; c < 8; ++c) {
      u16x4 p4;
      p4[0] = f2bf(acc[c][0] * rinv);
      p4[1] = f2bf(acc[c][1] * rinv);
      p4[2] = f2bf(acc[c][2] * rinv);
      p4[3] = f2bf(acc[c][3] * rinv);
      *reinterpret_cast<u16x4*>(prow + ((wcb + c * 16 + lq * 4) ^ swz)) = p4;
    }
  }
  __syncthreads();

  // coalesced wout writeback: wave w -> rows {2w, 2w+1}; half-wave = 512B runs
  {
    const int row = wave * 2 + (lane >> 5);
    const int cb = (lane & 31) * 4;
    const u16* pr = Pl + row * 1024;
    const int sw = (row & 7) << 3;
    float* wrow = wout + ((size_t)((b * H_ + h) * NT_ + qt * 16 + row)) * NS_;
#pragma unroll
    for (int ch = 0; ch < 8; ++ch) {
      const int e = ch * 128 + cb;
      u16x4 p4 = *reinterpret_cast<const u16x4*>(pr + (e ^ sw));
      f32x4 w4;
      w4[0] = bf2f(p4[0]); w4[1] = bf2f(p4[1]);
      w4[2] = bf2f(p4[2]); w4[3] = bf2f(p4[3]);
      __builtin_nontemporal_store(w4, reinterpret_cast<f32x4*>(wrow + e));
    }
  }

  // Phase B: ctx[16][64] = P @ V.  wave -> (k-half, d-quarter)
  const int kh = wave >> 2, dq = wave & 3;
  const u16* prow2 = Pl + l15 * 1024;           // A-frag row t = l15
  const int swz2 = (l15 & 7) << 3;
  const u16* vbase = vpT + ((size_t)((b * H_ + h) * HD_ + dq * 16 + l15)) * NS_
                   + kh * 512 + lq * 8;
  f32x4 acc2 = (f32x4){0.f, 0.f, 0.f, 0.f};
#pragma unroll
  for (int ks = 0; ks < 16; ++ks) {
    short8 pa = *reinterpret_cast<const short8*>(
        prow2 + ((kh * 512 + ks * 32 + lq * 8) ^ swz2));
    short8 vf = *reinterpret_cast<const short8*>(vbase + ks * 32);
    acc2 = mfma16(pa, vf, acc2);
  }
  // combine k-halves: kh=0 stores partial to LDS, kh=1 adds and writes out
  if (kh == 0) {
#pragma unroll
    for (int r = 0; r < 4; ++r)
      ctxp[(lq * 4 + r) * 64 + dq * 16 + l15] = acc2[r];
  }
  __syncthreads();
  if (kh == 1) {
    u16* cbase = ctx + ((size_t)(b * NT_ + qt * 16 + lq * 4)) * D_ + h * HD_ + dq * 16 + l15;
#pragma unroll
    for (int r = 0; r < 4; ++r) {
      const float v = acc2[r] + ctxp[(lq * 4 + r) * 64 + dq * 16 + l15];
      cbase[(size_t)r * D_] = f2bf(v);
    }
  }
}

// ---------------------------------------------------------------- launch
extern "C" void kernel_launch(void* const* d_in, const int* in_sizes, int n_in,
                              void* d_out, int out_size, void* d_ws, size_t ws_size,
                              hipStream_t stream) {
  const float* q   = (const float*)d_in[0];
  const float* k   = (const float*)d_in[1];
  const float* v   = (const float*)d_in[2];
  const float* q_w = (const float*)d_in[3];
  const float* k_w = (const float*)d_in[4];
  const float* v_w = (const float*)d_in[5];
  const float* o_w = (const float*)d_in[6];
  const float* b_q = (const float*)d_in[7];
  const float* b_k = (const float*)d_in[8];
  const float* b_v = (const float*)d_in[9];
  const float* b_o = (const float*)d_in[10];
  const float* msk = (const float*)d_in[11];

  float* out = (float*)d_out;                       // [B,NT,D]
  float* wout = out + (size_t)B_ * NT_ * D_;        // [B,H,NT,NS]

  // workspace layout (bf16 elements)
  u16* qb = (u16*)d_ws;            // 4M   @0
  u16* kb = qb + 4194304;          //      @8MB
  u16* vb = kb + 4194304;          //      @16MB
  u16* wq = vb + 4194304;          // 1M   @24MB
  u16* wk = wq + 1048576;          //      @26MB
  u16* wv = wk + 1048576;          //      @28MB
  u16* wo = wv + 1048576;          //      @30MB
  u16* qp = wo + 1048576;          // 4M   @32MB
  u16* kp = qp + 4194304;          //      @40MB
  u16* vp = kp + 4194304;          //      @48MB  (total 56MB)
  u16* vpT = qb;                   // reuse: q bf16 dead after projections
  u16* ctx = kb;                   // reuse: k bf16 dead after projections

  CvtArgs ca;
  ca.src[0] = q;   ca.dst[0] = qb; ca.n[0] = B_ * NT_ * D_;
  ca.src[1] = k;   ca.dst[1] = kb; ca.n[1] = B_ * NS_ * D_;
  ca.src[2] = v;   ca.dst[2] = vb; ca.n[2] = B_ * NS_ * D_;
  ca.src[3] = q_w; ca.dst[3] = wq; ca.n[3] = D_ * D_;
  ca.src[4] = k_w; ca.dst[4] = wk; ca.n[4] = D_ * D_;
  ca.src[5] = v_w; ca.dst[5] = wv; ca.n[5] = D_ * D_;
  ca.src[6] = o_w; ca.dst[6] = wo; ca.n[6] = D_ * D_;
  cvt_kernel<<<dim3(1024, 1, 7), 256, 0, stream>>>(ca);

  qkv_gemm_kernel<<<dim3(8, 32, 3), 256, 0, stream>>>(
      qb, kb, vb, wq, wk, wv, b_q, b_k, b_v, qp, kp, vp);

  vtrans_kernel<<<dim3(16, 16, 4), 256, 0, stream>>>(vp, vpT);

  attn_kernel<<<dim3(64, 16, 4), 512, 0, stream>>>(qp, kp, vpT, msk, wout, ctx);

  oproj_kernel<<<dim3(8, 32), 256, 0, stream>>>(ctx, wo, b_o, out);
}